// Round 5
// baseline (172.174 us; speedup 1.0000x reference)
//
#include <hip/hip_runtime.h>

#define N_EMB 8192
#define DIM   1024
#define NPAIR 65536
#define MARGIN 1.0f

typedef _Float16 h2 __attribute__((ext_vector_type(2)));
typedef _Float16 h4 __attribute__((ext_vector_type(4)));
typedef _Float16 h8 __attribute__((ext_vector_type(8)));

// ===================== fp16-table path =====================
// ws layout: [0] double acc, [8] uint cnt, [64..) fp16 normalized table (16 MB)

// Kernel A: normalize each row in fp32, store as fp16 (+ zero acc/cnt).
// One block (256 threads) per row; thread t owns elements 4t..4t+3.
__global__ __launch_bounds__(256) void prep16_kernel(const float* __restrict__ emb,
                                                     _Float16* __restrict__ nemb,
                                                     double* __restrict__ acc,
                                                     unsigned int* __restrict__ cnt) {
    const int row = blockIdx.x;
    const int tid = threadIdx.x;
    const float4 v = reinterpret_cast<const float4*>(emb + (size_t)row * DIM)[tid];
    float s = v.x * v.x + v.y * v.y + v.z * v.z + v.w * v.w;
    #pragma unroll
    for (int off = 32; off > 0; off >>= 1) s += __shfl_xor(s, off);
    __shared__ float part[4];
    if ((tid & 63) == 0) part[tid >> 6] = s;
    __syncthreads();
    const float rn = 1.0f / sqrtf(part[0] + part[1] + part[2] + part[3]);
    h4 o;
    o[0] = (_Float16)(v.x * rn);
    o[1] = (_Float16)(v.y * rn);
    o[2] = (_Float16)(v.z * rn);
    o[3] = (_Float16)(v.w * rn);
    reinterpret_cast<h4*>(nemb + (size_t)row * DIM)[tid] = o;
    if (row == 0 && tid == 0) { *acc = 0.0; *cnt = 0u; }
}

// Kernel B: pair gather (fp16 rows, 2KB each) + dot + hinge + reduce.
// One wave per pair per iteration; lane l reads 16B at l and l+64 of each row
// (64 lanes x 16B = 1KB per load instruction, 2 loads per row).
__global__ __launch_bounds__(256) void pair16_kernel(const _Float16* __restrict__ nemb,
                                                     const int* __restrict__ ind1,
                                                     const int* __restrict__ ind2,
                                                     const int* __restrict__ tgt,
                                                     double* __restrict__ acc,
                                                     unsigned int* __restrict__ cnt,
                                                     float* __restrict__ out) {
    const int lane   = threadIdx.x & 63;
    const int wave   = (blockIdx.x * blockDim.x + threadIdx.x) >> 6;
    const int nwaves = (gridDim.x * blockDim.x) >> 6;

    float wsum = 0.0f;

    for (int p = wave; p < NPAIR; p += nwaves) {
        const int a = ind1[p];
        const int b = ind2[p];
        const h8* ra = reinterpret_cast<const h8*>(nemb + (size_t)a * DIM);
        const h8* rb = reinterpret_cast<const h8*>(nemb + (size_t)b * DIM);

        const h8 a0 = ra[lane];
        const h8 a1 = ra[lane + 64];
        const h8 b0 = rb[lane];
        const h8 b1 = rb[lane + 64];

        float s = 0.0f;
#if __has_builtin(__builtin_amdgcn_fdot2)
        #define FD(va, vb, I) do { h2 xa, xb;                                  \
            xa[0] = va[2*I]; xa[1] = va[2*I + 1];                              \
            xb[0] = vb[2*I]; xb[1] = vb[2*I + 1];                              \
            s = __builtin_amdgcn_fdot2(xa, xb, s, false); } while (0)
        FD(a0, b0, 0); FD(a0, b0, 1); FD(a0, b0, 2); FD(a0, b0, 3);
        FD(a1, b1, 0); FD(a1, b1, 1); FD(a1, b1, 2); FD(a1, b1, 3);
        #undef FD
#else
        #pragma unroll
        for (int i = 0; i < 8; ++i) {
            s = fmaf((float)a0[i], (float)b0[i], s);
            s = fmaf((float)a1[i], (float)b1[i], s);
        }
#endif
        // wave reduce -> lane 0 holds full dot
        #pragma unroll
        for (int off = 32; off > 0; off >>= 1) s += __shfl_xor(s, off);

        if (lane == 0) {
            const float dist = 1.0f - s;   // rows pre-normalized
            const float t    = (float)tgt[p];
            wsum += t * dist + (1.0f - t) * fmaxf(MARGIN - dist, 0.0f);
        }
    }

    __shared__ float part[4];
    if (lane == 0) part[threadIdx.x >> 6] = wsum;
    __syncthreads();
    if (threadIdx.x == 0) {
        atomicAdd(acc, (double)(part[0] + part[1] + part[2] + part[3]));
        __threadfence();
        const unsigned int done = atomicAdd(cnt, 1u);
        if (done == gridDim.x - 1) {                 // last block finalizes
            const double tot = atomicAdd(acc, 0.0);  // device-scope read
            out[0] = (float)(tot / (double)NPAIR);
        }
    }
}

// ===================== fp32 fallback path (ws too small) =====================

__global__ __launch_bounds__(256) void norms_kernel(const float* __restrict__ emb,
                                                    float* __restrict__ rnorm,
                                                    double* __restrict__ acc,
                                                    unsigned int* __restrict__ cnt) {
    const int row = blockIdx.x;
    const int tid = threadIdx.x;
    const float4 v = reinterpret_cast<const float4*>(emb + (size_t)row * DIM)[tid];
    float s = v.x * v.x + v.y * v.y + v.z * v.z + v.w * v.w;
    #pragma unroll
    for (int off = 32; off > 0; off >>= 1) s += __shfl_xor(s, off);
    __shared__ float part[4];
    if ((tid & 63) == 0) part[tid >> 6] = s;
    __syncthreads();
    if (tid == 0) {
        rnorm[row] = 1.0f / sqrtf(part[0] + part[1] + part[2] + part[3]);
        if (row == 0) { *acc = 0.0; *cnt = 0u; }
    }
}

__global__ __launch_bounds__(256) void pair32_kernel(const float* __restrict__ emb,
                                                     const float* __restrict__ rnorm,
                                                     const int* __restrict__ ind1,
                                                     const int* __restrict__ ind2,
                                                     const int* __restrict__ tgt,
                                                     double* __restrict__ acc,
                                                     unsigned int* __restrict__ cnt,
                                                     float* __restrict__ out) {
    const int lane   = threadIdx.x & 63;
    const int wave   = (blockIdx.x * blockDim.x + threadIdx.x) >> 6;
    const int nwaves = (gridDim.x * blockDim.x) >> 6;
    float wsum = 0.0f;
    for (int p = wave; p < NPAIR; p += nwaves) {
        const int a = ind1[p];
        const int b = ind2[p];
        const float4* ra = reinterpret_cast<const float4*>(emb + (size_t)a * DIM);
        const float4* rb = reinterpret_cast<const float4*>(emb + (size_t)b * DIM);
        const float4 a0 = ra[lane];
        const float4 a1 = ra[lane + 64];
        const float4 a2 = ra[lane + 128];
        const float4 a3 = ra[lane + 192];
        const float4 b0 = rb[lane];
        const float4 b1 = rb[lane + 64];
        const float4 b2 = rb[lane + 128];
        const float4 b3 = rb[lane + 192];
        float s = a0.x * b0.x;
        s = fmaf(a0.y, b0.y, s); s = fmaf(a0.z, b0.z, s); s = fmaf(a0.w, b0.w, s);
        s = fmaf(a1.x, b1.x, s); s = fmaf(a1.y, b1.y, s); s = fmaf(a1.z, b1.z, s); s = fmaf(a1.w, b1.w, s);
        s = fmaf(a2.x, b2.x, s); s = fmaf(a2.y, b2.y, s); s = fmaf(a2.z, b2.z, s); s = fmaf(a2.w, b2.w, s);
        s = fmaf(a3.x, b3.x, s); s = fmaf(a3.y, b3.y, s); s = fmaf(a3.z, b3.z, s); s = fmaf(a3.w, b3.w, s);
        #pragma unroll
        for (int off = 32; off > 0; off >>= 1) s += __shfl_xor(s, off);
        if (lane == 0) {
            const float dist = 1.0f - s * rnorm[a] * rnorm[b];
            const float t    = (float)tgt[p];
            wsum += t * dist + (1.0f - t) * fmaxf(MARGIN - dist, 0.0f);
        }
    }
    __shared__ float part[4];
    if (lane == 0) part[threadIdx.x >> 6] = wsum;
    __syncthreads();
    if (threadIdx.x == 0) {
        atomicAdd(acc, (double)(part[0] + part[1] + part[2] + part[3]));
        __threadfence();
        const unsigned int done = atomicAdd(cnt, 1u);
        if (done == gridDim.x - 1) {
            const double tot = atomicAdd(acc, 0.0);
            out[0] = (float)(tot / (double)NPAIR);
        }
    }
}

extern "C" void kernel_launch(void* const* d_in, const int* in_sizes, int n_in,
                              void* d_out, int out_size, void* d_ws, size_t ws_size,
                              hipStream_t stream) {
    const float* emb  = (const float*)d_in[0];
    const int*   ind1 = (const int*)d_in[1];
    const int*   ind2 = (const int*)d_in[2];
    const int*   tgt  = (const int*)d_in[3];
    float*       out  = (float*)d_out;

    double*       acc = (double*)d_ws;
    unsigned int* cnt = (unsigned int*)((char*)d_ws + 8);

    const size_t table_bytes = (size_t)N_EMB * DIM * sizeof(_Float16); // 16 MB

    if (ws_size >= 64 + table_bytes) {
        _Float16* nemb = (_Float16*)((char*)d_ws + 64);
        prep16_kernel<<<N_EMB, 256, 0, stream>>>(emb, nemb, acc, cnt);
        pair16_kernel<<<2048, 256, 0, stream>>>(nemb, ind1, ind2, tgt, acc, cnt, out);
    } else {
        float* rnorm = (float*)((char*)d_ws + 64);
        norms_kernel<<<N_EMB, 256, 0, stream>>>(emb, rnorm, acc, cnt);
        pair32_kernel<<<2048, 256, 0, stream>>>(emb, rnorm, ind1, ind2, tgt, acc, cnt, out);
    }
}